// Round 1
// baseline (108.443 us; speedup 1.0000x reference)
//
#include <hip/hip_runtime.h>

// AllAtomFAPE: B=2, N_RES=256, N_FR=8, N_AT=14
// out[b] = sum_{f,a} min(sqrt(|R_p^T(x_p-t_p) - R_t^T(x_t-t_t)|^2 + eps), 10) * m_fa
//          / (max(sum m_fa, 1) * 10)
// m_fa = (seq[r_f]*frame_mask[f]) * (atom_mask[a]*true_atom_mask[a]*seq[r_a])

constexpr int B_    = 2;
constexpr int NRES  = 256;
constexpr int NFR   = 8;
constexpr int NAT   = 14;
constexpr int NF    = NRES * NFR;   // 2048 frames per batch
constexpr int NA    = NRES * NAT;   // 3584 atoms per batch

constexpr int FT    = 64;           // frames per block (1 per 4-thread group)
constexpr int ATILE = 224;          // atoms per block tile
constexpr int FBLK  = NF / FT;      // 32
constexpr int ABLK  = NA / ATILE;   // 16
constexpr int NBLOCKS = B_ * FBLK * ABLK;  // 1024 blocks -> 4 per CU

#define EPS_F   1e-4f
#define DCLAMP  10.0f
#define Z_F     10.0

__global__ __launch_bounds__(256) void fape_main(
    const float* __restrict__ pR,   // [B, NF, 3, 3]
    const float* __restrict__ pT,   // [B, NF, 3]
    const float* __restrict__ pPos, // [B, NA, 3]
    const float* __restrict__ aM,   // [B, NA]
    const float* __restrict__ tR,   // [B, NF, 3, 3]
    const float* __restrict__ tT,   // [B, NF, 3]
    const float* __restrict__ tPos, // [B, NA, 3]
    const float* __restrict__ tAM,  // [B, NA]
    const float* __restrict__ seqM, // [B, NRES]
    const float* __restrict__ frM,  // [B, NF]  (== [B, NRES, NFR])
    double* __restrict__ ws)        // [B][2] : num, den (pre-zeroed)
{
    __shared__ float sPR[FT * 9];
    __shared__ float sTR[FT * 9];
    __shared__ float sPT[FT * 3];
    __shared__ float sTT[FT * 3];
    __shared__ float sFM[FT];
    __shared__ float sAP[ATILE * 3];
    __shared__ float sTP[ATILE * 3];
    __shared__ float sAM[ATILE];
    __shared__ float sRed[8];  // 4 waves x {num, den}

    const int bid  = blockIdx.x;
    const int b    = bid / (FBLK * ABLK);
    const int rem  = bid % (FBLK * ABLK);
    const int fblk = rem / ABLK;
    const int ablk = rem % ABLK;
    const int f0   = fblk * FT;
    const int a0   = ablk * ATILE;
    const int tid  = threadIdx.x;

    // ---- stage frame tile (coalesced contiguous copies) ----
    {
        const float* gpR = pR + (size_t)(b * NF + f0) * 9;
        const float* gtR = tR + (size_t)(b * NF + f0) * 9;
        for (int i = tid; i < FT * 9; i += 256) { sPR[i] = gpR[i]; sTR[i] = gtR[i]; }
        const float* gpT = pT + (size_t)(b * NF + f0) * 3;
        const float* gtT = tT + (size_t)(b * NF + f0) * 3;
        for (int i = tid; i < FT * 3; i += 256) { sPT[i] = gpT[i]; sTT[i] = gtT[i]; }
        if (tid < FT) {
            const int f = f0 + tid;
            sFM[tid] = seqM[b * NRES + f / NFR] * frM[b * NF + f];
        }
    }
    // ---- stage atom tile ----
    {
        const float* gpP = pPos + (size_t)(b * NA + a0) * 3;
        const float* gtP = tPos + (size_t)(b * NA + a0) * 3;
        for (int i = tid; i < ATILE * 3; i += 256) { sAP[i] = gpP[i]; sTP[i] = gtP[i]; }
        if (tid < ATILE) {
            const int a = a0 + tid;
            sAM[tid] = aM[b * NA + a] * tAM[b * NA + a] * seqM[b * NRES + a / NAT];
        }
    }
    __syncthreads();

    // ---- per-thread frame registers ----
    const int fl  = tid >> 2;   // local frame 0..63
    const int sub = tid & 3;    // atom sub-lane 0..3

    float pr[9], trr[9];
    #pragma unroll
    for (int k = 0; k < 9; ++k) { pr[k] = sPR[fl * 9 + k]; trr[k] = sTR[fl * 9 + k]; }
    const float ptx = sPT[fl * 3 + 0], pty = sPT[fl * 3 + 1], ptz = sPT[fl * 3 + 2];
    const float ttx = sTT[fl * 3 + 0], tty = sTT[fl * 3 + 1], ttz = sTT[fl * 3 + 2];
    const float fm  = sFM[fl];

    float num = 0.f, den = 0.f;
    // Each group of 4 threads covers all ATILE atoms for its frame.
    for (int ai = sub; ai < ATILE; ai += 4) {
        const float am = sAM[ai];
        const float pdx = sAP[ai * 3 + 0] - ptx;
        const float pdy = sAP[ai * 3 + 1] - pty;
        const float pdz = sAP[ai * 3 + 2] - ptz;
        const float tdx = sTP[ai * 3 + 0] - ttx;
        const float tdy = sTP[ai * 3 + 1] - tty;
        const float tdz = sTP[ai * 3 + 2] - ttz;
        // local = R^T * d  => local_i = R[0][i]*d0 + R[1][i]*d1 + R[2][i]*d2
        const float lpx = pr[0] * pdx + pr[3] * pdy + pr[6] * pdz;
        const float lpy = pr[1] * pdx + pr[4] * pdy + pr[7] * pdz;
        const float lpz = pr[2] * pdx + pr[5] * pdy + pr[8] * pdz;
        const float ltx = trr[0] * tdx + trr[3] * tdy + trr[6] * tdz;
        const float lty = trr[1] * tdx + trr[4] * tdy + trr[7] * tdz;
        const float ltz = trr[2] * tdx + trr[5] * tdy + trr[8] * tdz;
        const float dx = lpx - ltx, dy = lpy - lty, dz = lpz - ltz;
        float e = sqrtf(dx * dx + dy * dy + dz * dz + EPS_F);
        e = fminf(e, DCLAMP);
        num += e * am;
        den += am;
    }
    num *= fm;   // frame mask factors out of the atom loop
    den *= fm;

    // ---- block reduction: wave64 butterfly -> LDS -> one atomic pair ----
    #pragma unroll
    for (int off = 32; off > 0; off >>= 1) {
        num += __shfl_down(num, off);
        den += __shfl_down(den, off);
    }
    const int wave = tid >> 6;
    const int lane = tid & 63;
    if (lane == 0) { sRed[wave * 2 + 0] = num; sRed[wave * 2 + 1] = den; }
    __syncthreads();
    if (tid == 0) {
        const float n = sRed[0] + sRed[2] + sRed[4] + sRed[6];
        const float d = sRed[1] + sRed[3] + sRed[5] + sRed[7];
        atomicAdd(&ws[b * 2 + 0], (double)n);
        atomicAdd(&ws[b * 2 + 1], (double)d);
    }
}

__global__ __launch_bounds__(64) void fape_final(const double* __restrict__ ws,
                                                 float* __restrict__ out)
{
    const int b = threadIdx.x;
    if (b < B_) {
        const double n = ws[b * 2 + 0];
        double d = ws[b * 2 + 1];
        d = d > 1.0 ? d : 1.0;
        out[b] = (float)(n / (d * Z_F));
    }
}

extern "C" void kernel_launch(void* const* d_in, const int* in_sizes, int n_in,
                              void* d_out, int out_size, void* d_ws, size_t ws_size,
                              hipStream_t stream)
{
    const float* pR   = (const float*)d_in[0];
    const float* pT   = (const float*)d_in[1];
    const float* pPos = (const float*)d_in[2];
    const float* aM   = (const float*)d_in[3];
    const float* tR   = (const float*)d_in[4];
    const float* tT   = (const float*)d_in[5];
    const float* tPos = (const float*)d_in[6];
    const float* tAM  = (const float*)d_in[7];
    const float* seqM = (const float*)d_in[8];
    const float* frM  = (const float*)d_in[9];

    double* ws = (double*)d_ws;

    hipMemsetAsync(d_ws, 0, B_ * 2 * sizeof(double), stream);
    fape_main<<<NBLOCKS, 256, 0, stream>>>(pR, pT, pPos, aM, tR, tT, tPos, tAM,
                                           seqM, frM, ws);
    fape_final<<<1, 64, 0, stream>>>(ws, (float*)d_out);
}

// Round 4
// 95.549 us; speedup vs baseline: 1.1349x; 1.1349x over previous
//
#include <hip/hip_runtime.h>

// AllAtomFAPE: B=2, N_RES=256, N_FR=8, N_AT=14
// out[b] = sum_{f,a} min(sqrt(|Rp^T(xp-tp) - Rt^T(xt-tt)|^2 + eps), 10) * m_fa
//          / (max(sum m_fa, 1) * 10)
// m_fa = (seq[r_f]*frame_mask[f]) * (atom_mask[a]*true_atom_mask[a]*seq[r_a])
//
// Structure (round 2/3/4): TWO launches, no memset, no atomics.
//  k1: 1024 blocks -> each writes a float2 {num,den} partial to d_ws[bid]
//  k2: 1 block x 1024 threads -> fp64 reduce of the 1024 partials -> out[2]

constexpr int B_    = 2;
constexpr int NRES  = 256;
constexpr int NFR   = 8;
constexpr int NAT   = 14;
constexpr int NF    = NRES * NFR;   // 2048 frames per batch
constexpr int NA    = NRES * NAT;   // 3584 atoms per batch

constexpr int FT    = 64;           // frames per block (1 per 4-thread group)
constexpr int ATILE = 224;          // atoms per block tile
constexpr int FBLK  = NF / FT;      // 32
constexpr int ABLK  = NA / ATILE;   // 16
constexpr int BLK_PER_B = FBLK * ABLK;      // 512
constexpr int NBLOCKS   = B_ * BLK_PER_B;   // 1024 blocks -> 4 per CU

#define EPS_F   1e-4f
#define DCLAMP  10.0f

__global__ __launch_bounds__(256) void fape_main(
    const float* __restrict__ pR,   // [B, NF, 3, 3]
    const float* __restrict__ pT,   // [B, NF, 3]
    const float* __restrict__ pPos, // [B, NA, 3]
    const float* __restrict__ aM,   // [B, NA]
    const float* __restrict__ tR,   // [B, NF, 3, 3]
    const float* __restrict__ tT,   // [B, NF, 3]
    const float* __restrict__ tPos, // [B, NA, 3]
    const float* __restrict__ tAM,  // [B, NA]
    const float* __restrict__ seqM, // [B, NRES]
    const float* __restrict__ frM,  // [B, NF]
    float2* __restrict__ parts)     // [NBLOCKS] block partials {num, den}
{
    __shared__ float  sPR[FT * 9];
    __shared__ float  sTR[FT * 9];
    __shared__ float  sPT[FT * 3];
    __shared__ float  sTT[FT * 3];
    __shared__ float  sFM[FT];
    __shared__ float4 sA[ATILE];    // {pred x,y,z, combined atom mask}
    __shared__ float4 sT4[ATILE];   // {true x,y,z, 0}
    __shared__ float  sRed[8];      // 4 waves x {num, den}

    const int bid  = blockIdx.x;
    const int b    = bid / BLK_PER_B;
    const int rem  = bid % BLK_PER_B;
    const int fblk = rem / ABLK;
    const int ablk = rem % ABLK;
    const int f0   = fblk * FT;
    const int a0   = ablk * ATILE;
    const int tid  = threadIdx.x;

    // ---- stage frame tile (coalesced contiguous copies) ----
    {
        const float* gpR = pR + (size_t)(b * NF + f0) * 9;
        const float* gtR = tR + (size_t)(b * NF + f0) * 9;
        for (int i = tid; i < FT * 9; i += 256) { sPR[i] = gpR[i]; sTR[i] = gtR[i]; }
        const float* gpT = pT + (size_t)(b * NF + f0) * 3;
        const float* gtT = tT + (size_t)(b * NF + f0) * 3;
        if (tid < FT * 3) { sPT[tid] = gpT[tid]; sTT[tid] = gtT[tid]; }
        if (tid < FT) {
            const int f = f0 + tid;
            sFM[tid] = seqM[b * NRES + f / NFR] * frM[b * NF + f];
        }
    }
    // ---- stage atom tile, packed as float4 ----
    if (tid < ATILE) {
        const int a = a0 + tid;
        const float* gp = pPos + (size_t)(b * NA + a) * 3;
        const float* gt = tPos + (size_t)(b * NA + a) * 3;
        const float am  = aM[b * NA + a] * tAM[b * NA + a] * seqM[b * NRES + a / NAT];
        sA[tid]  = make_float4(gp[0], gp[1], gp[2], am);
        sT4[tid] = make_float4(gt[0], gt[1], gt[2], 0.f);
    }
    __syncthreads();

    // ---- per-thread frame registers ----
    const int fl  = tid >> 2;   // local frame 0..63
    const int sub = tid & 3;    // atom sub-lane 0..3

    float pr[9], trr[9];
    #pragma unroll
    for (int k = 0; k < 9; ++k) { pr[k] = sPR[fl * 9 + k]; trr[k] = sTR[fl * 9 + k]; }
    const float ptx = sPT[fl * 3 + 0], pty = sPT[fl * 3 + 1], ptz = sPT[fl * 3 + 2];
    const float ttx = sTT[fl * 3 + 0], tty = sTT[fl * 3 + 1], ttz = sTT[fl * 3 + 2];
    const float fm  = sFM[fl];

    float num = 0.f, den = 0.f;
    // Each 4-thread group covers all ATILE atoms for its frame.
    #pragma unroll 4
    for (int ai = sub; ai < ATILE; ai += 4) {
        const float4 ap = sA[ai];   // one ds_read_b128 (4 distinct addrs/wave)
        const float4 tp = sT4[ai];  // one ds_read_b128
        const float pdx = ap.x - ptx, pdy = ap.y - pty, pdz = ap.z - ptz;
        const float tdx = tp.x - ttx, tdy = tp.y - tty, tdz = tp.z - ttz;
        // local = R^T * d
        const float lpx = pr[0] * pdx + pr[3] * pdy + pr[6] * pdz;
        const float lpy = pr[1] * pdx + pr[4] * pdy + pr[7] * pdz;
        const float lpz = pr[2] * pdx + pr[5] * pdy + pr[8] * pdz;
        const float ltx = trr[0] * tdx + trr[3] * tdy + trr[6] * tdz;
        const float lty = trr[1] * tdx + trr[4] * tdy + trr[7] * tdz;
        const float ltz = trr[2] * tdx + trr[5] * tdy + trr[8] * tdz;
        const float dx = lpx - ltx, dy = lpy - lty, dz = lpz - ltz;
        float e = sqrtf(dx * dx + dy * dy + dz * dz + EPS_F);
        e = fminf(e, DCLAMP);
        num += e * ap.w;
        den += ap.w;
    }
    num *= fm;
    den *= fm;

    // ---- block reduction: wave64 butterfly -> LDS -> one float2 store ----
    #pragma unroll
    for (int off = 32; off > 0; off >>= 1) {
        num += __shfl_down(num, off);
        den += __shfl_down(den, off);
    }
    const int wave = tid >> 6;
    if ((tid & 63) == 0) { sRed[wave * 2 + 0] = num; sRed[wave * 2 + 1] = den; }
    __syncthreads();
    if (tid == 0) {
        parts[bid] = make_float2(sRed[0] + sRed[2] + sRed[4] + sRed[6],
                                 sRed[1] + sRed[3] + sRed[5] + sRed[7]);
    }
}

__global__ __launch_bounds__(1024) void fape_reduce(
    const float2* __restrict__ parts,  // [NBLOCKS], first 512 are b=0
    float* __restrict__ out)           // [B_]
{
    __shared__ double sn[16], sd[16];
    const int tid = threadIdx.x;              // 0..1023
    const float2 p = parts[tid];
    double n = (double)p.x, d = (double)p.y;
    #pragma unroll
    for (int off = 32; off > 0; off >>= 1) {
        n += __shfl_down(n, off);
        d += __shfl_down(d, off);
    }
    const int wave = tid >> 6;                // 0..15; waves 0-7 are b=0
    if ((tid & 63) == 0) { sn[wave] = n; sd[wave] = d; }
    __syncthreads();
    if (tid < B_) {
        double N = 0.0, D = 0.0;
        #pragma unroll
        for (int i = 0; i < 8; ++i) { N += sn[tid * 8 + i]; D += sd[tid * 8 + i]; }
        D = D > 1.0 ? D : 1.0;
        out[tid] = (float)(N / (D * 10.0));
    }
}

extern "C" void kernel_launch(void* const* d_in, const int* in_sizes, int n_in,
                              void* d_out, int out_size, void* d_ws, size_t ws_size,
                              hipStream_t stream)
{
    const float* pR   = (const float*)d_in[0];
    const float* pT   = (const float*)d_in[1];
    const float* pPos = (const float*)d_in[2];
    const float* aM   = (const float*)d_in[3];
    const float* tR   = (const float*)d_in[4];
    const float* tT   = (const float*)d_in[5];
    const float* tPos = (const float*)d_in[6];
    const float* tAM  = (const float*)d_in[7];
    const float* seqM = (const float*)d_in[8];
    const float* frM  = (const float*)d_in[9];

    float2* parts = (float2*)d_ws;   // 1024 * 8 B = 8 KiB; fully overwritten by k1

    fape_main<<<NBLOCKS, 256, 0, stream>>>(pR, pT, pPos, aM, tR, tT, tPos, tAM,
                                           seqM, frM, parts);
    fape_reduce<<<1, 1024, 0, stream>>>(parts, (float*)d_out);
}